// Round 15
// baseline (52.313 us; speedup 1.0000x reference)
//
#include <hip/hip_runtime.h>

typedef short short8 __attribute__((ext_vector_type(8)));
typedef float f32x4 __attribute__((ext_vector_type(4)));

#define DK 64
#define BM 64     // users per block
#define BN 128    // movies per block

// f32 -> bf16 round-to-nearest-even
__device__ __forceinline__ short f2bf(float x) {
    unsigned u = __builtin_bit_cast(unsigned, x);
    unsigned r = (u + 0x7fffu + ((u >> 16) & 1u)) >> 16;
    return (short)r;
}

// elementwise bf16 square of a bf16x8 fragment (exact f32 product,
// round-half-up repack — error ~2^-9 rel, negligible vs threshold)
__device__ __forceinline__ short8 sq8(short8 v) {
    short8 r;
#pragma unroll
    for (int i = 0; i < 8; ++i) {
        unsigned u = ((unsigned)(unsigned short)v[i]) << 16;
        float f = __builtin_bit_cast(float, u);
        unsigned p = __builtin_bit_cast(unsigned, f * f);
        r[i] = (short)((p + 0x8000u) >> 16);
    }
    return r;
}

// convert 8 consecutive f32 to a bf16x8
__device__ __forceinline__ short8 cvt8(const float* s) {
    float4 a = *(const float4*)(s);
    float4 b = *(const float4*)(s + 4);
    return (short8){ f2bf(a.x), f2bf(a.y), f2bf(a.z), f2bf(a.w),
                     f2bf(b.x), f2bf(b.y), f2bf(b.z), f2bf(b.w) };
}

// ---------------- Fused single-kernel: convert-in-block + double-GEMM -------
// Eliminates the serialized convert dispatch (~5-6 us): each block converts
// its OWN A tile (16 KB f32) and B tile (32 KB f32) from the original inputs
// straight into XOR-swizzled LDS (values only, 24 KB), then runs the R10
// champion GEMM body (sq8 in-reg squares, transposed MFMA, f32x4 stores).
// Consecutive blocks (x-fastest) share the B tile -> XCD-L2 hits; read
// traffic is not the limiter (R12). 4 blocks/CU as before.
__global__ __launch_bounds__(256, 4)
void fm_fused(const float* __restrict__ U, const float* __restrict__ M,
              float* __restrict__ out, int NU, int NM) {
    __shared__ short sA[BM * DK];    // 8 KB user values (swizzled)
    __shared__ short sB[BN * DK];    // 16 KB movie values (swizzled) -> 24 KB

    const int t = threadIdx.x;
    const int lane = t & 63;
    const int w = t >> 6;            // wave 0..3 -> movie quadrant (32 cols)
    const int lr = lane & 15;
    const int lk = lane >> 4;

    const int ub  = blockIdx.x * BM;   // user base
    const int nb0 = blockIdx.y * BN;   // movie base

    // ---- stage + convert: A (512 chunk8 tasks), B (1024 tasks) ----
    // task idx -> row = idx>>3, p = idx&7 (8-float chunk); write swizzled:
    // sX[row*64 + ((p ^ (row&7))<<3)]. Wave reads are then conflict-free.
#pragma unroll
    for (int j = 0; j < 2; ++j) {
        const int idx = t + 256 * j;
        const int row = idx >> 3;
        const int p = idx & 7;
        short8 v = cvt8(U + (size_t)(ub + row) * DK + p * 8);
        *(short8*)&sA[row * DK + ((p ^ (row & 7)) << 3)] = v;
    }
#pragma unroll
    for (int j = 0; j < 4; ++j) {
        const int idx = t + 256 * j;
        const int row = idx >> 3;
        const int p = idx & 7;
        const int grow = nb0 + row;
        short8 v = {0,0,0,0,0,0,0,0};
        if (grow < NM)
            v = cvt8(M + (size_t)grow * DK + p * 8);
        *(short8*)&sB[row * DK + ((p ^ (row & 7)) << 3)] = v;
    }
    __syncthreads();

    // ---- B value fragments (squares recomputed per-n) ----
    short8 bv[2][2];                 // movies: [n][ks], wave quadrant
#pragma unroll
    for (int n = 0; n < 2; ++n)
#pragma unroll
        for (int ks = 0; ks < 2; ++ks) {
            const int row = w * 32 + n * 16 + lr;
            const int c = ks * 4 + lk;
            const int idx = row * DK + ((c ^ (row & 7)) << 3);
            bv[n][ks] = *(const short8*)&sB[idx];
        }

    const int nbW = nb0 + w * 32;

    // ---- per-m: A frags, derived squares, 8 MFMAs, 2 stores ----
#pragma unroll
    for (int m = 0; m < 4; ++m) {
        short8 av0, av1, aq0, aq1;
        {
            const int row = m * 16 + lr;
            const int i0 = row * DK + (((0 * 4 + lk) ^ (row & 7)) << 3);
            const int i1 = row * DK + (((1 * 4 + lk) ^ (row & 7)) << 3);
            av0 = *(const short8*)&sA[i0];
            av1 = *(const short8*)&sA[i1];
            aq0 = sq8(av0);
            aq1 = sq8(av1);
        }

        f32x4 s[2], q[2];
#pragma unroll
        for (int n = 0; n < 2; ++n) {
            s[n] = (f32x4){0.f, 0.f, 0.f, 0.f};
            q[n] = (f32x4){0.f, 0.f, 0.f, 0.f};
        }
#pragma unroll
        for (int n = 0; n < 2; ++n) {
            // transposed: D[movie][user] -> lane holds user col lr,
            // 4 consecutive movie cols lk*4+reg (layout proven R5-R14)
            const short8 bq0 = sq8(bv[n][0]);
            const short8 bq1 = sq8(bv[n][1]);
            s[n] = __builtin_amdgcn_mfma_f32_16x16x32_bf16(bv[n][0], av0, s[n], 0, 0, 0);
            s[n] = __builtin_amdgcn_mfma_f32_16x16x32_bf16(bv[n][1], av1, s[n], 0, 0, 0);
            q[n] = __builtin_amdgcn_mfma_f32_16x16x32_bf16(bq0, aq0, q[n], 0, 0, 0);
            q[n] = __builtin_amdgcn_mfma_f32_16x16x32_bf16(bq1, aq1, q[n], 0, 0, 0);
        }

        float* rowp = out + (size_t)(ub + m * 16 + lr) * NM;
#pragma unroll
        for (int n = 0; n < 2; ++n) {
            const int col = nbW + n * 16 + lk * 4;
            if (col < NM) {
                f32x4 sv = s[n], qv = q[n];
                f32x4 rr;
#pragma unroll
                for (int j = 0; j < 4; ++j)
                    rr[j] = 0.5f * (sv[j] * sv[j] - qv[j]);
                *(f32x4*)(rowp + col) = rr;
            }
        }
    }
}

// ---------------- Fallback (round-1 kernel, self-contained) -----------------
__global__ __launch_bounds__(256, 2)
void fm_fallback(const float* __restrict__ U, const float* __restrict__ M,
                 float* __restrict__ out, int NU, int NM) {
    __shared__ short sA [128 * DK];
    __shared__ short sA2[128 * DK];
    __shared__ short sB [128 * DK];
    __shared__ short sB2[128 * DK];

    const int t = threadIdx.x;
    const int lane = t & 63;
    const int w = t >> 6;
    const int wr = w >> 1;
    const int wc = w & 1;
    const int lr = lane & 15;
    const int lk = lane >> 4;

    const int mbase = blockIdx.x * 128;
    const int nbase = blockIdx.y * 128;

    const int r0 = t >> 4;
    const int c4 = t & 15;
    const int chunk = c4 >> 1;
    const int sub = c4 & 1;

    typedef short short4v __attribute__((ext_vector_type(4)));
#pragma unroll
    for (int i = 0; i < 8; ++i) {
        const int r = r0 + i * 16;
        const int sidx = r * DK + ((chunk ^ (r & 7)) << 3) + (sub << 2);
        {
            float4 v = make_float4(0.f, 0.f, 0.f, 0.f);
            const int gr = mbase + r;
            if (gr < NU) v = *(const float4*)(U + (size_t)gr * DK + c4 * 4);
            short4v b  = { f2bf(v.x), f2bf(v.y), f2bf(v.z), f2bf(v.w) };
            short4v b2 = { f2bf(v.x*v.x), f2bf(v.y*v.y), f2bf(v.z*v.z), f2bf(v.w*v.w) };
            *(short4v*)&sA[sidx] = b; *(short4v*)&sA2[sidx] = b2;
        }
        {
            float4 v = make_float4(0.f, 0.f, 0.f, 0.f);
            const int gr = nbase + r;
            if (gr < NM) v = *(const float4*)(M + (size_t)gr * DK + c4 * 4);
            short4v b  = { f2bf(v.x), f2bf(v.y), f2bf(v.z), f2bf(v.w) };
            short4v b2 = { f2bf(v.x*v.x), f2bf(v.y*v.y), f2bf(v.z*v.z), f2bf(v.w*v.w) };
            *(short4v*)&sB[sidx] = b; *(short4v*)&sB2[sidx] = b2;
        }
    }
    __syncthreads();

    f32x4 accS[4][4], accQ[4][4];
#pragma unroll
    for (int m = 0; m < 4; ++m)
#pragma unroll
        for (int n = 0; n < 4; ++n) {
            accS[m][n] = (f32x4){0.f,0.f,0.f,0.f};
            accQ[m][n] = (f32x4){0.f,0.f,0.f,0.f};
        }
#pragma unroll
    for (int ks = 0; ks < 2; ++ks) {
        short8 af[4], a2f[4], bfr[4], b2f[4];
        const int c = ks * 4 + lk;
#pragma unroll
        for (int m = 0; m < 4; ++m) {
            const int row = wr * 64 + m * 16 + lr;
            const int idx = row * DK + ((c ^ (row & 7)) << 3);
            af[m] = *(const short8*)&sA[idx]; a2f[m] = *(const short8*)&sA2[idx];
        }
#pragma unroll
        for (int n = 0; n < 4; ++n) {
            const int row = wc * 64 + n * 16 + lr;
            const int idx = row * DK + ((c ^ (row & 7)) << 3);
            bfr[n] = *(const short8*)&sB[idx]; b2f[n] = *(const short8*)&sB2[idx];
        }
#pragma unroll
        for (int m = 0; m < 4; ++m)
#pragma unroll
            for (int n = 0; n < 4; ++n) {
                accS[m][n] = __builtin_amdgcn_mfma_f32_16x16x32_bf16(af[m],  bfr[n], accS[m][n], 0, 0, 0);
                accQ[m][n] = __builtin_amdgcn_mfma_f32_16x16x32_bf16(a2f[m], b2f[n], accQ[m][n], 0, 0, 0);
            }
    }
#pragma unroll
    for (int m = 0; m < 4; ++m) {
        const int grow0 = mbase + wr * 64 + m * 16 + lk * 4;
#pragma unroll
        for (int n = 0; n < 4; ++n) {
            const int gcol = nbase + wc * 64 + n * 16 + lr;
            if (gcol < NM) {
                f32x4 s = accS[m][n]; f32x4 q = accQ[m][n];
#pragma unroll
                for (int r = 0; r < 4; ++r) {
                    const int grow = grow0 + r;
                    if (grow < NU)
                        out[(size_t)grow * NM + gcol] = 0.5f * (s[r]*s[r] - q[r]);
                }
            }
        }
    }
}

extern "C" void kernel_launch(void* const* d_in, const int* in_sizes, int n_in,
                              void* d_out, int out_size, void* d_ws, size_t ws_size,
                              hipStream_t stream) {
    const float* U = (const float*)d_in[0];
    const float* M = (const float*)d_in[1];
    float* out = (float*)d_out;
    const int NU = in_sizes[0] / DK;   // 1024
    const int NM = in_sizes[1] / DK;   // 50000
    const int NMP = ((NM + BN - 1) / BN) * BN;

    if ((NU % BM == 0) && (NM % 4 == 0)) {
        dim3 grid(NU / BM, NMP / BN);
        fm_fused<<<grid, dim3(256), 0, stream>>>(U, M, out, NU, NM);
    } else {
        dim3 grid((NU + 127) / 128, (NM + 127) / 128);
        fm_fallback<<<grid, dim3(256), 0, stream>>>(U, M, out, NU, NM);
    }
}

// Round 16
// 50.489 us; speedup vs baseline: 1.0361x; 1.0361x over previous
//
#include <hip/hip_runtime.h>

typedef short short8 __attribute__((ext_vector_type(8)));
typedef float f32x4 __attribute__((ext_vector_type(4)));

#define DK 64
#define BM 64     // users per block
#define BN 128    // movies per block

// f32 -> bf16 round-to-nearest-even
__device__ __forceinline__ short f2bf(float x) {
    unsigned u = __builtin_bit_cast(unsigned, x);
    unsigned r = (u + 0x7fffu + ((u >> 16) & 1u)) >> 16;
    return (short)r;
}

// elementwise bf16 square of a bf16x8 fragment (exact f32 product,
// round-half-up repack — error ~2^-9 rel, negligible vs threshold)
__device__ __forceinline__ short8 sq8(short8 v) {
    short8 r;
#pragma unroll
    for (int i = 0; i < 8; ++i) {
        unsigned u = ((unsigned)(unsigned short)v[i]) << 16;
        float f = __builtin_bit_cast(float, u);
        unsigned p = __builtin_bit_cast(unsigned, f * f);
        r[i] = (short)((p + 0x8000u) >> 16);
    }
    return r;
}

__device__ __forceinline__ void gl_lds16(const void* g, void* l) {
    __builtin_amdgcn_global_load_lds(
        (const __attribute__((address_space(1))) unsigned int*)g,
        (__attribute__((address_space(3))) unsigned int*)l, 16, 0, 0);
}

// ---------------- Phase 1: bf16 convert (VALUES ONLY), pre-swizzled ---------
// ws (shorts): [wsU: NUP*64][wsM: NMP*64]  (~6.5 MB — LLC/L2 resident)
// Rows stored with 16B chunk p holding source chunk p^(row&7): a LINEAR
// global_load_lds copy then yields the XOR-swizzled LDS layout (rule #21).
__global__ __launch_bounds__(256)
void fm_convert(const float* __restrict__ U, const float* __restrict__ M,
                short* __restrict__ ws, int NU, int NM, int NUP, int NMP) {
    int id = blockIdx.x * blockDim.x + threadIdx.x;
    int total = (NUP + NMP) * 8;
    if (id >= total) return;
    int rowg = id >> 3;
    int p = id & 7;                 // 16B chunk within the 64-wide row
    const float* src; short* dv; int row, nvalid;
    if (rowg < NUP) {
        row = rowg; src = U; dv = ws; nvalid = NU;
    } else {
        row = rowg - NUP; src = M;
        dv = ws + (size_t)NUP * DK; nvalid = NM;
    }
    short8 v8 = {0,0,0,0,0,0,0,0};
    if (row < nvalid) {
        const int cp = p ^ (row & 7);
        const float* s = src + (size_t)row * DK + cp * 8;
        float4 a = *(const float4*)(s);
        float4 b = *(const float4*)(s + 4);
        v8 = (short8){ f2bf(a.x), f2bf(a.y), f2bf(a.z), f2bf(a.w),
                       f2bf(b.x), f2bf(b.y), f2bf(b.z), f2bf(b.w) };
    }
    *(short8*)(dv + (size_t)row * DK + p * 8) = v8;
}

// ---------------- Phase 2: single-shot fused double-GEMM, 24 KB LDS ---------
// CHAMPION (R10, 50.74 us). Single-shot, one barrier, values-only staging
// via global_load_lds, squares derived in-register (sq8), per-m epilogue,
// transposed MFMA -> f32x4 normal stores. 4 blocks/CU.
// Plateau evidence (R9-R15): 51-52 us across staging volume 38-300 MB,
// occupancy 3-5 blk/CU, tiles 64x128/128x128/64x256, store granularity
// 16B-512B, NT vs normal, fused vs two-phase -> tiled-output write-BW
// ceiling ~4.5 TB/s is the binding constraint.
__global__ __launch_bounds__(256, 6)
void fm_gemm(const short* __restrict__ ws, float* __restrict__ out,
             int NM, int NMP, int NUP) {
    __shared__ short sA[BM * DK];    // 8 KB user values
    __shared__ short sB[BN * DK];    // 16 KB movie values -> 24 KB total

    const int t = threadIdx.x;
    const int lane = t & 63;
    const int w = t >> 6;            // wave 0..3 -> movie quadrant (32 cols)
    const int lr = lane & 15;
    const int lk = lane >> 4;

    const int ub  = blockIdx.x * BM;   // user base
    const int nb0 = blockIdx.y * BN;   // movie base

    const short* gU = ws;
    const short* gM = ws + (size_t)NUP * DK;

    // ---- stage: A 8 KB + B 16 KB via global_load_lds (linear dest) ----
    {
        const short* srcA = gU + (size_t)ub * DK;
        const short* srcB = gM + (size_t)nb0 * DK;
        const int lo = lane * 8;                  // lane's 16B in a 1KB chunk
#pragma unroll
        for (int j = 0; j < 2; ++j) {             // A: 8 chunks / 4 waves
            const int ch = w * 2 + j;
            gl_lds16(srcA + ch * 512 + lo, &sA[ch * 512]);
        }
#pragma unroll
        for (int j = 0; j < 4; ++j) {             // B: 16 chunks / 4 waves
            const int ch = w * 4 + j;
            gl_lds16(srcB + ch * 512 + lo, &sB[ch * 512]);
        }
    }
    __syncthreads();

    // ---- B value fragments only (squares recomputed per-m) ----
    short8 bv[2][2];                 // movies: [n][ks], wave quadrant
#pragma unroll
    for (int n = 0; n < 2; ++n)
#pragma unroll
        for (int ks = 0; ks < 2; ++ks) {
            const int row = w * 32 + n * 16 + lr;
            const int c = ks * 4 + lk;
            const int idx = row * DK + ((c ^ (row & 7)) << 3);
            bv[n][ks] = *(const short8*)&sB[idx];
        }

    const int nbW = nb0 + w * 32;

    // ---- per-m: load A frags, derive squares, 8 MFMAs, 2 stores ----
#pragma unroll
    for (int m = 0; m < 4; ++m) {
        short8 av0, av1, aq0, aq1;
        {
            const int row = m * 16 + lr;
            const int i0 = row * DK + (((0 * 4 + lk) ^ (row & 7)) << 3);
            const int i1 = row * DK + (((1 * 4 + lk) ^ (row & 7)) << 3);
            av0 = *(const short8*)&sA[i0];
            av1 = *(const short8*)&sA[i1];
            aq0 = sq8(av0);
            aq1 = sq8(av1);
        }

        f32x4 s[2], q[2];
#pragma unroll
        for (int n = 0; n < 2; ++n) {
            s[n] = (f32x4){0.f, 0.f, 0.f, 0.f};
            q[n] = (f32x4){0.f, 0.f, 0.f, 0.f};
        }
#pragma unroll
        for (int n = 0; n < 2; ++n) {
            // transposed: D[movie][user] -> lane holds user col lr,
            // 4 consecutive movie cols lk*4+reg (layout proven R5-R15)
            const short8 bq0 = sq8(bv[n][0]);
            const short8 bq1 = sq8(bv[n][1]);
            s[n] = __builtin_amdgcn_mfma_f32_16x16x32_bf16(bv[n][0], av0, s[n], 0, 0, 0);
            s[n] = __builtin_amdgcn_mfma_f32_16x16x32_bf16(bv[n][1], av1, s[n], 0, 0, 0);
            q[n] = __builtin_amdgcn_mfma_f32_16x16x32_bf16(bq0, aq0, q[n], 0, 0, 0);
            q[n] = __builtin_amdgcn_mfma_f32_16x16x32_bf16(bq1, aq1, q[n], 0, 0, 0);
        }

        float* rowp = out + (size_t)(ub + m * 16 + lr) * NM;
#pragma unroll
        for (int n = 0; n < 2; ++n) {
            const int col = nbW + n * 16 + lk * 4;
            if (col < NM) {
                f32x4 sv = s[n], qv = q[n];
                f32x4 rr;
#pragma unroll
                for (int j = 0; j < 4; ++j)
                    rr[j] = 0.5f * (sv[j] * sv[j] - qv[j]);
                *(f32x4*)(rowp + col) = rr;
            }
        }
    }
}

// ---------------- Fallback (round-1 kernel, self-contained) -----------------
__global__ __launch_bounds__(256, 2)
void fm_fallback(const float* __restrict__ U, const float* __restrict__ M,
                 float* __restrict__ out, int NU, int NM) {
    __shared__ short sA [128 * DK];
    __shared__ short sA2[128 * DK];
    __shared__ short sB [128 * DK];
    __shared__ short sB2[128 * DK];

    const int t = threadIdx.x;
    const int lane = t & 63;
    const int w = t >> 6;
    const int wr = w >> 1;
    const int wc = w & 1;
    const int lr = lane & 15;
    const int lk = lane >> 4;

    const int mbase = blockIdx.x * 128;
    const int nbase = blockIdx.y * 128;

    const int r0 = t >> 4;
    const int c4 = t & 15;
    const int chunk = c4 >> 1;
    const int sub = c4 & 1;

    typedef short short4v __attribute__((ext_vector_type(4)));
#pragma unroll
    for (int i = 0; i < 8; ++i) {
        const int r = r0 + i * 16;
        const int sidx = r * DK + ((chunk ^ (r & 7)) << 3) + (sub << 2);
        {
            float4 v = make_float4(0.f, 0.f, 0.f, 0.f);
            const int gr = mbase + r;
            if (gr < NU) v = *(const float4*)(U + (size_t)gr * DK + c4 * 4);
            short4v b  = { f2bf(v.x), f2bf(v.y), f2bf(v.z), f2bf(v.w) };
            short4v b2 = { f2bf(v.x*v.x), f2bf(v.y*v.y), f2bf(v.z*v.z), f2bf(v.w*v.w) };
            *(short4v*)&sA[sidx] = b; *(short4v*)&sA2[sidx] = b2;
        }
        {
            float4 v = make_float4(0.f, 0.f, 0.f, 0.f);
            const int gr = nbase + r;
            if (gr < NM) v = *(const float4*)(M + (size_t)gr * DK + c4 * 4);
            short4v b  = { f2bf(v.x), f2bf(v.y), f2bf(v.z), f2bf(v.w) };
            short4v b2 = { f2bf(v.x*v.x), f2bf(v.y*v.y), f2bf(v.z*v.z), f2bf(v.w*v.w) };
            *(short4v*)&sB[sidx] = b; *(short4v*)&sB2[sidx] = b2;
        }
    }
    __syncthreads();

    f32x4 accS[4][4], accQ[4][4];
#pragma unroll
    for (int m = 0; m < 4; ++m)
#pragma unroll
        for (int n = 0; n < 4; ++n) {
            accS[m][n] = (f32x4){0.f,0.f,0.f,0.f};
            accQ[m][n] = (f32x4){0.f,0.f,0.f,0.f};
        }
#pragma unroll
    for (int ks = 0; ks < 2; ++ks) {
        short8 af[4], a2f[4], bfr[4], b2f[4];
        const int c = ks * 4 + lk;
#pragma unroll
        for (int m = 0; m < 4; ++m) {
            const int row = wr * 64 + m * 16 + lr;
            const int idx = row * DK + ((c ^ (row & 7)) << 3);
            af[m] = *(const short8*)&sA[idx]; a2f[m] = *(const short8*)&sA2[idx];
        }
#pragma unroll
        for (int n = 0; n < 4; ++n) {
            const int row = wc * 64 + n * 16 + lr;
            const int idx = row * DK + ((c ^ (row & 7)) << 3);
            bfr[n] = *(const short8*)&sB[idx]; b2f[n] = *(const short8*)&sB2[idx];
        }
#pragma unroll
        for (int m = 0; m < 4; ++m)
#pragma unroll
            for (int n = 0; n < 4; ++n) {
                accS[m][n] = __builtin_amdgcn_mfma_f32_16x16x32_bf16(af[m],  bfr[n], accS[m][n], 0, 0, 0);
                accQ[m][n] = __builtin_amdgcn_mfma_f32_16x16x32_bf16(a2f[m], b2f[n], accQ[m][n], 0, 0, 0);
            }
    }
#pragma unroll
    for (int m = 0; m < 4; ++m) {
        const int grow0 = mbase + wr * 64 + m * 16 + lk * 4;
#pragma unroll
        for (int n = 0; n < 4; ++n) {
            const int gcol = nbase + wc * 64 + n * 16 + lr;
            if (gcol < NM) {
                f32x4 s = accS[m][n]; f32x4 q = accQ[m][n];
#pragma unroll
                for (int r = 0; r < 4; ++r) {
                    const int grow = grow0 + r;
                    if (grow < NU)
                        out[(size_t)grow * NM + gcol] = 0.5f * (s[r]*s[r] - q[r]);
                }
            }
        }
    }
}

extern "C" void kernel_launch(void* const* d_in, const int* in_sizes, int n_in,
                              void* d_out, int out_size, void* d_ws, size_t ws_size,
                              hipStream_t stream) {
    const float* U = (const float*)d_in[0];
    const float* M = (const float*)d_in[1];
    float* out = (float*)d_out;
    const int NU = in_sizes[0] / DK;   // 1024
    const int NM = in_sizes[1] / DK;   // 50000
    const int NUP = NU;
    const int NMP = ((NM + BN - 1) / BN) * BN;
    const size_t need = (size_t)(NUP + NMP) * DK * sizeof(short);

    if ((NU % BM == 0) && (NM % 4 == 0) && ws_size >= need) {
        short* ws = (short*)d_ws;
        const int tasks = (NUP + NMP) * 8;
        fm_convert<<<(tasks + 255) / 256, 256, 0, stream>>>(U, M, ws, NU, NM, NUP, NMP);
        dim3 grid(NU / BM, NMP / BN);
        fm_gemm<<<grid, dim3(256), 0, stream>>>(ws, out, NM, NMP, NUP);
    } else {
        dim3 grid((NU + 127) / 128, (NM + 127) / 128);
        fm_fallback<<<grid, dim3(256), 0, stream>>>(U, M, out, NU, NM);
    }
}